// Round 8
// baseline (489.943 us; speedup 1.0000x reference)
//
#include <hip/hip_runtime.h>
#include <hip/hip_bf16.h>

typedef __bf16 bfx8 __attribute__((ext_vector_type(8)));
typedef __bf16 bfx4 __attribute__((ext_vector_type(4)));
typedef float  f32x4 __attribute__((ext_vector_type(4)));
typedef float  f32x16 __attribute__((ext_vector_type(16)));

#define MFMA16(a,b,c) __builtin_amdgcn_mfma_f32_16x16x32_bf16((a),(b),(c),0,0,0)
#define MFMA32(a,b,c) __builtin_amdgcn_mfma_f32_32x32x16_bf16((a),(b),(c),0,0,0)

// B=4, SM=1024, SI=4096, D=256, H=8, FF=1024
// External I/O: float32. Internal: bf16 operands + f32 accumulation.

// exp(min(s*0.0625, 30)) == exp2(min(s*0.0625*log2e, 30*log2e))
#define PSCALE 0.09016844f
#define PCLAMP 43.2808512f

__device__ __forceinline__ unsigned cvtpk_bf16(float lo, float hi) {
  unsigned d;
  asm("v_cvt_pk_bf16_f32 %0, %1, %2" : "=v"(d) : "v"(lo), "v"(hi));
  return d;
}

// Assemble one P A-fragment (bfx8, k = h*8+j) from 8 per-lane probabilities.
// After swapped QK^T (S^T), lane (l31,h) holds P[q=l31][key=(r&3)+8*(r>>2)+4h].
// cvt_pk pairs + two permlane32_swap (hi<->lo half exchange) complete the
// in-register transpose slice — replaces the LDS round trip.
__device__ __forceinline__ bfx8 packswap(const float* p) {
  unsigned a = cvtpk_bf16(p[0], p[1]);
  unsigned b = cvtpk_bf16(p[2], p[3]);
  unsigned c = cvtpk_bf16(p[4], p[5]);
  unsigned d = cvtpk_bf16(p[6], p[7]);
  asm("v_permlane32_swap_b32 %0, %1" : "+v"(a), "+v"(c));
  asm("v_permlane32_swap_b32 %0, %1" : "+v"(b), "+v"(d));
  union { unsigned u[4]; bfx8 v; } uu;
  uu.u[0] = a; uu.u[1] = b; uu.u[2] = c; uu.u[3] = d;
  return uu.v;
}

// ---------------- coalesced 64x64 tile transpose (f32 -> bf16^T) ----------------
__device__ __forceinline__ void tile_tr(const float* __restrict__ src, __bf16* __restrict__ dst,
                                        int R, int C, int tile, float (*lt)[65]) {
  int tpr = C >> 6;
  int tr = tile / tpr, tc = tile % tpr;
  int c  = threadIdx.x & 63;
  int r0 = (threadIdx.x >> 6) << 4;
  const float* sp = src + (long)(tr * 64 + r0) * C + tc * 64 + c;
#pragma unroll
  for (int i = 0; i < 16; i++) lt[r0 + i][c] = sp[(long)i * C];
  __syncthreads();
  __bf16* dp = dst + (long)(tc * 64 + r0) * R + tr * 64 + c;
#pragma unroll
  for (int i = 0; i < 16; i++) dp[(long)i * R] = (__bf16)lt[c][r0 + i];
}

__global__ void trans_attn_t(const float* __restrict__ Wk, const float* __restrict__ Wv,
                             const float* __restrict__ Wq, const float* __restrict__ Wo,
                             __bf16* __restrict__ wkvqt, __bf16* __restrict__ wot) {
  __shared__ float lt[64][65];
  int t = blockIdx.x;
  if (t < 16)       tile_tr(Wk, wkvqt, 256, 256, t, lt);
  else if (t < 32)  tile_tr(Wv, wkvqt + 65536, 256, 256, t - 16, lt);
  else if (t < 160) {
    int e = t - 32, m = e >> 4;
    tile_tr(Wq + (long)m * 65536, wkvqt + 131072 + (long)m * 65536, 256, 256, e & 15, lt);
  } else            tile_tr(Wo, wot, 2048, 256, t - 160, lt);
}

__global__ void trans_ffn_t(const float* __restrict__ W_in, const float* __restrict__ Wg_nl,
                            const float* __restrict__ Wg_l, const float* __restrict__ Wg_o,
                            __bf16* __restrict__ dst) {
  __shared__ float lt[64][65];
  int t = blockIdx.x;
  if (t < 64)       tile_tr(W_in, dst, 256, 1024, t, lt);
  else if (t < 320) tile_tr(Wg_nl, dst + 262144, 1024, 1024, t - 64, lt);
  else if (t < 576) tile_tr(Wg_l, dst + 1310720, 1024, 1024, t - 320, lt);
  else              tile_tr(Wg_o, dst + 2359296, 1024, 256, t - 576, lt);
}

// ---------------- GEMM body: C[M,N] = act(X[M,K] @ Wt[N,K]^T + bias) ----------------
// xmode: 0 bf16 X (row stride Kfull); 1 f32 X; 2 gated bf16 (stride 2048, x=a*b pairs k,k+1024)
// mode: 0 plain; 4 K|V split; 5 K|V|Q split; 6 dual-act (relu iff n<1024);
//       7 split-K f32 partials: Cf[z*M*N + m*N + n] (bias added in z==0 slice)
__device__ __forceinline__
void gemm_body(const __bf16* __restrict__ Xb, const float* __restrict__ Xf,
               const __bf16* __restrict__ Wt,
               const float* __restrict__ b1, const float* __restrict__ b2,
               const float* __restrict__ b3,
               __bf16* __restrict__ C, __bf16* __restrict__ C2, __bf16* __restrict__ C3,
               float* __restrict__ Cf,
               int M, int N, int Kfull, int kspan, int xmode, int mode, int act,
               int bx, int by, int bz, __bf16* xs, __bf16* wsm) {
  const int tid  = threadIdx.x;
  const int lane = tid & 63;
  const int w    = tid >> 6;
  const int l15  = lane & 15;
  const int quad = lane >> 4;
  const int wm   = (w >> 1) * 64;
  const int wn   = (w & 1) * 64;
  const int m0   = bx * 128;
  const int n0   = by * 128;
  const int k0   = (mode == 7) ? bz * kspan : 0;

  f32x4 acc[4][4];
#pragma unroll
  for (int i = 0; i < 4; i++)
#pragma unroll
    for (int j = 0; j < 4; j++) acc[i][j] = (f32x4){0.f, 0.f, 0.f, 0.f};

  for (int kk = k0; kk < k0 + kspan; kk += 64) {
    __syncthreads();
#pragma unroll
    for (int rep = 0; rep < 4; rep++) {
      int idx = rep * 256 + tid;
      int row = idx >> 3;
      int g   = idx & 7;
      if (xmode == 1) {
        const float* p = Xf + (long)(m0 + row) * Kfull + kk + g * 8;
        f32x4 a0 = *(const f32x4*)p;
        f32x4 a1 = *(const f32x4*)(p + 4);
        bfx8 v;
#pragma unroll
        for (int j = 0; j < 4; j++) { v[j] = (__bf16)a0[j]; v[4 + j] = (__bf16)a1[j]; }
        *(bfx8*)&xs[row * 72 + g * 8] = v;
      } else if (xmode == 2) {
        const __bf16* p = Xb + (long)(m0 + row) * 2048 + kk + g * 8;
        bfx8 a = *(const bfx8*)p;
        bfx8 bb = *(const bfx8*)(p + 1024);
        bfx8 v;
#pragma unroll
        for (int j = 0; j < 8; j++) v[j] = (__bf16)((float)a[j] * (float)bb[j]);
        *(bfx8*)&xs[row * 72 + g * 8] = v;
      } else {
        *(bfx8*)&xs[row * 72 + g * 8] = *(const bfx8*)(Xb + (long)(m0 + row) * Kfull + kk + g * 8);
      }
      *(bfx8*)&wsm[row * 72 + g * 8] = *(const bfx8*)(Wt + (long)(n0 + row) * Kfull + kk + g * 8);
    }
    __syncthreads();
#pragma unroll
    for (int ks = 0; ks < 2; ks++) {
      bfx8 af[4], bf_[4];
#pragma unroll
      for (int i = 0; i < 4; i++) af[i]  = *(const bfx8*)&xs[(wm + 16 * i + l15) * 72 + ks * 32 + quad * 8];
#pragma unroll
      for (int j = 0; j < 4; j++) bf_[j] = *(const bfx8*)&wsm[(wn + 16 * j + l15) * 72 + ks * 32 + quad * 8];
#pragma unroll
      for (int i = 0; i < 4; i++)
#pragma unroll
        for (int j = 0; j < 4; j++) acc[i][j] = MFMA16(af[i], bf_[j], acc[i][j]);
    }
  }

#pragma unroll
  for (int j = 0; j < 4; j++) {
    int n = n0 + wn + 16 * j + l15;
    float bv;
    if (mode == 4)      bv = (n < 256) ? b1[n] : b2[n - 256];
    else if (mode == 5) bv = (n < 256) ? b1[n] : (n < 512) ? b2[n - 256] : b3[n - 512];
    else if (mode == 6) bv = (n < 1024) ? b1[n] : b2[n - 1024];
    else if (mode == 7) bv = (bz == 0) ? b1[n] : 0.f;
    else                bv = b1[n];
#pragma unroll
    for (int i = 0; i < 4; i++) {
#pragma unroll
      for (int r = 0; r < 4; r++) {
        int m = m0 + wm + 16 * i + quad * 4 + r;   // C/D layout: row = quad*4+reg
        float v = acc[i][j][r] + bv;
        if (mode == 6) { if (n < 1024) v = fmaxf(v, 0.f); }
        else if (act == 1) v = fmaxf(v, 0.f);
        if (mode == 4) {
          if (n < 256) C[(long)m * 256 + n] = (__bf16)v;
          else {
            int bb_ = m >> 12, si = m & 4095;
            C2[((long)(bb_ * 128 + (si >> 5)) * 256 + (n - 256)) * 32 + (si & 31)] = (__bf16)v;
          }
        } else if (mode == 5) {
          if (n < 256)      C[(long)m * 256 + n] = (__bf16)v;
          else if (n < 512) C2[(long)m * 256 + (n - 256)] = (__bf16)v;
          else {
            int nn = n - 512, hhh = nn >> 8, dd = nn & 255;
            C3[(long)hhh * 1048576 + (long)m * 256 + dd] = (__bf16)v;
          }
        } else if (mode == 7) {
          Cf[(long)bz * M * N + (long)m * N + n] = v;
        } else {
          C[(long)m * N + n] = (__bf16)v;
        }
      }
    }
  }
}

__global__ __launch_bounds__(256)
void gemm_bt(const __bf16* Xb, const float* Xf, const __bf16* Wt,
             const float* b1, const float* b2, const float* b3,
             __bf16* C, __bf16* C2, __bf16* C3, float* Cf,
             int M, int N, int Kfull, int kspan, int xmode, int mode, int act) {
  __shared__ __bf16 xs[128 * 72];
  __shared__ __bf16 wsm[128 * 72];
  gemm_body(Xb, Xf, Wt, b1, b2, b3, C, C2, C3, Cf, M, N, Kfull, kspan, xmode, mode, act,
            blockIdx.x, blockIdx.y, blockIdx.z, xs, wsm);
}

// merged K|V input projection (blocks 0..511, grid (128,4)) + K|V|Q state projection
// (blocks 512..1151, grid (32,20)) — both depend only on trans_attn_t.
__global__ __launch_bounds__(256)
void proj2(const float* input, const float* state, const __bf16* Wkvqt,
           const float* bk, const float* bv, const float* bq,
           __bf16* ik, __bf16* ivT, __bf16* mk, __bf16* mv, __bf16* qbuf) {
  __shared__ __bf16 xs[128 * 72];
  __shared__ __bf16 wsm[128 * 72];
  int bid = blockIdx.x;
  if (bid < 512) {
    gemm_body(nullptr, input, Wkvqt, bk, bv, nullptr, ik, ivT, nullptr, nullptr,
              16384, 512, 256, 256, 1, 4, 0, bid & 127, bid >> 7, 0, xs, wsm);
  } else {
    int b2 = bid - 512;
    gemm_body(nullptr, state, Wkvqt, bk, bv, bq, mk, mv, qbuf, nullptr,
              4096, 2560, 256, 256, 1, 5, 0, b2 & 31, b2 >> 5, 0, xs, wsm);
  }
}

// ------- fused multi-query attention (r15: wave role-specialization) -------
// grid (SM/64, B, H) = 512 blocks, 4 waves (256 thr). Block owns 64 Q-rows.
// Waves 0-1 (S-waves, row-group=w): hold Q frags, compute S(i+1) [16 MFMA32],
//   softmax finishP, publish P A-frags to a 4 KB LDS buffer.
// Waves 2-3 (PV-waves, row-group=w-2): hold full-d oacc [128 acc regs],
//   read P(i) frags, compute PV(i) [16 MFMA32]. No Q, no S — no duplication.
// Perfectly balanced 16 MFMA/wave/chunk; same total MFMA as the r9 kernel but
// 512 blocks x 4 waves = 2 waves/SIMD (per-path regs ~195 <= 256; LDS 78.8 KB
// -> 2 blocks/CU). r14 proved the occupancy mechanism (occ 20%, MfmaUtil 42%)
// but paid 1.5x duplicated S; this removes the duplication.
// Sync: single P buffer, 2 barriers/chunk (A: P(i) reads done before S writes
// P(i+1); B: staged K/V + P(i+1) visible). Both divergent paths execute
// identical barrier counts (258) — wave-specialization pattern.
// Staging: both paths run the same tid-indexed staging code; S-threads
// (tid 0..127) + PV-threads (128..255) together cover the full chunk.
__global__ __attribute__((amdgpu_flat_work_group_size(256, 256)))
__attribute__((amdgpu_waves_per_eu(2, 2)))
void attn_kernel_s(const __bf16* __restrict__ qb,   // [H][B*SM][256]
                   const __bf16* __restrict__ ik,   // [B*SI][256]
                   const __bf16* __restrict__ ivT,  // [B][128][256][32]
                   const __bf16* __restrict__ mk,   // [B*SM][256]
                   const __bf16* __restrict__ mv,   // [B*SM][256]
                   __bf16* __restrict__ concat) {   // [B*SM][2048]
  __shared__ __bf16 lk[2][32][264];     // K chunks [buf][key][d], +8 pad  (33.8 KB)
  __shared__ __bf16 lvt[2][256][40];    // V^T chunks [buf][d][key], +8 pad (41 KB)
  __shared__ __bf16 pl[2][64][16];      // P A-frag exchange [rowgrp][lane]  (4 KB)

  const int tid  = threadIdx.x;
  const int lane = tid & 63;
  const int w    = tid >> 6;
  const int role = w >> 1;              // 0: S/softmax waves, 1: PV waves
  const int grp  = w & 1;               // row group (32 rows) within the block
  const int l31  = lane & 31;
  const int h    = lane >> 5;

  const int m0 = blockIdx.x * 64;
  const int b  = blockIdx.y;
  const int hh = blockIdx.z;
  const int mw = m0 + grp * 32;

  const long kvbase = (long)b * 4096 * 256;
  const long vtbase = (long)b * 128 * 8192;
  const long mbase  = ((long)b * 1024 + mw) * 256;

  auto sload_k = [&](int c, bfx8* kreg) {
    const long kb = kvbase + (long)c * 8192;
#pragma unroll
    for (int rep = 0; rep < 4; rep++) {
      int idx = rep * 256 + tid;
      kreg[rep] = *(const bfx8*)(ik + kb + (long)(idx >> 5) * 256 + (idx & 31) * 8);
    }
  };
  auto sload_v = [&](int c, bfx8* vreg) {
    const long vb = vtbase + (long)c * 8192;
#pragma unroll
    for (int rep = 0; rep < 4; rep++) {
      int idx = rep * 256 + tid;
      vreg[rep] = *(const bfx8*)(ivT + vb + (long)idx * 8);
    }
  };
  auto sstore_k = [&](int slot, const bfx8* kreg) {
#pragma unroll
    for (int rep = 0; rep < 4; rep++) {
      int idx = rep * 256 + tid;
      *(bfx8*)&lk[slot][idx >> 5][(idx & 31) * 8] = kreg[rep];
    }
  };
  auto sstore_v = [&](int slot, const bfx8* vreg) {
#pragma unroll
    for (int rep = 0; rep < 4; rep++) {
      int idx = rep * 256 + tid;
      *(bfx8*)&lvt[slot][idx >> 2][(idx & 3) * 8] = vreg[rep];
    }
  };

  float* ex = (float*)&pl[0][0][0];     // end-of-kernel tot/ps exchange (512 B)

  if (role == 0) {
    // ===================== S / softmax waves =====================
    bfx8 qf[16];
    {
      const long qbase = ((long)hh * 4096 + b * 1024 + mw) * 256;
      const __bf16* qrow = qb + qbase + (long)l31 * 256 + h * 8;
#pragma unroll
      for (int kt = 0; kt < 16; kt++) qf[kt] = *(const bfx8*)(qrow + kt * 16);
    }
    float ps_l;
    {
      const __bf16* krow = mk + mbase + (long)l31 * 256 + h * 8;
      float s = 0.f;
#pragma unroll
      for (int kt = 0; kt < 16; kt++) {
        bfx8 kv = *(const bfx8*)(krow + kt * 16);
#pragma unroll
        for (int j = 0; j < 8; j++) s += (float)qf[kt][j] * (float)kv[j];
      }
      s += __shfl_xor(s, 32);
      ps_l = __builtin_amdgcn_exp2f(fminf(s * PSCALE, PCLAMP));
    }

    f32x16 zz;
#pragma unroll
    for (int i = 0; i < 16; i++) zz[i] = 0.f;
    f32x16 sa[4];
    float den_l = 0.f;

    auto chunkS = [&](int kslot) {
#pragma unroll
      for (int t = 0; t < 8; t++) {
        bfx8 kf0 = *(const bfx8*)&lk[kslot][l31][(2 * t) * 16 + h * 8];
        bfx8 kf1 = *(const bfx8*)&lk[kslot][l31][(2 * t + 1) * 16 + h * 8];
        if (t < 2) {
          sa[2 * t]     = MFMA32(kf0, qf[2 * t], zz);
          sa[2 * t + 1] = MFMA32(kf1, qf[2 * t + 1], zz);
        } else {
          sa[(2 * t) & 3]     = MFMA32(kf0, qf[2 * t], sa[(2 * t) & 3]);
          sa[(2 * t + 1) & 3] = MFMA32(kf1, qf[2 * t + 1], sa[(2 * t + 1) & 3]);
        }
      }
    };
    auto finishP = [&]() {                 // exp + pack + publish to LDS
      float p[16];
#pragma unroll
      for (int r = 0; r < 16; r++) {
        float s = (sa[0][r] + sa[1][r]) + (sa[2][r] + sa[3][r]);
        p[r] = __builtin_amdgcn_exp2f(fminf(s * PSCALE, PCLAMP));
        den_l += p[r];
      }
      bfx8 pf0 = packswap(p);
      bfx8 pf1 = packswap(p + 8);
      *(bfx8*)&pl[grp][lane][0] = pf0;
      *(bfx8*)&pl[grp][lane][8] = pf1;
    };

    {   // prologue staging: K(0)->lk0, K(1)->lk1, V(0)->lvt0
      bfx8 kreg[4], vreg[4];
      sload_k(0, kreg);
      sload_v(0, vreg);
      sstore_k(0, kreg);
      sstore_v(0, vreg);
      sload_k(1, kreg);
      sstore_k(1, kreg);
    }
    __syncthreads();                       // [1]
    chunkS(0);                             // S(0)
    finishP();                             // publish P(0)
    __syncthreads();                       // [2]

    for (int i = 0; i < 126; i++) {
      bfx8 kreg[4], vreg[4];
      sload_k(i + 2, kreg);
      sload_v(i + 1, vreg);
      __syncthreads();                     // A: PV consumed P(i)
      chunkS((i + 1) & 1);                 // S(i+1)
      sstore_k(i & 1, kreg);
      sstore_v((i + 1) & 1, vreg);
      finishP();                           // publish P(i+1)
      __syncthreads();                     // B
    }
    {   // i = 126
      bfx8 vreg[4];
      sload_v(127, vreg);
      __syncthreads();                     // A
      chunkS(1);                           // S(127)
      sstore_v(1, vreg);
      finishP();                           // publish P(127)
      __syncthreads();                     // B
    }
    // i = 127: PV-only chunk; then drop tot/ps into the dead P buffer
    __syncthreads();                       // C: PV loaded P(127)
    float den_row = den_l + __shfl_xor(den_l, 32);   // lane l31: row-l31 den
    ex[grp * 32 + l31]      = den_row + ps_l;        // tot
    ex[64 + grp * 32 + l31] = ps_l;                  // self weight
    __syncthreads();                       // D
  } else {
    // ===================== PV waves =====================
    f32x16 oacc[8];
#pragma unroll
    for (int dt = 0; dt < 8; dt++)
#pragma unroll
      for (int i = 0; i < 16; i++) oacc[dt][i] = 0.f;
    bfx8 pf0c, pf1c;

    auto pfload = [&]() {
      pf0c = *(const bfx8*)&pl[grp][lane][0];
      pf1c = *(const bfx8*)&pl[grp][lane][8];
    };
    auto chunkPV = [&](int vslot) {
#pragma unroll
      for (int t = 0; t < 8; t++) {
        bfx8 vf0 = *(const bfx8*)&lvt[vslot][t * 32 + l31][h * 8];
        bfx8 vf1 = *(const bfx8*)&lvt[vslot][t * 32 + l31][16 + h * 8];
        oacc[t] = MFMA32(pf0c, vf0, oacc[t]);
        oacc[t] = MFMA32(pf1c, vf1, oacc[t]);
      }
    };

    {   // prologue staging (mirrors S path; tid 128..255 half)
      bfx8 kreg[4], vreg[4];
      sload_k(0, kreg);
      sload_v(0, vreg);
      sstore_k(0, kreg);
      sstore_v(0, vreg);
      sload_k(1, kreg);
      sstore_k(1, kreg);
    }
    __syncthreads();                       // [1]
    __syncthreads();                       // [2]: P(0) visible

    for (int i = 0; i < 126; i++) {
      bfx8 kreg[4], vreg[4];
      sload_k(i + 2, kreg);
      sload_v(i + 1, vreg);
      pfload();                            // P(i)
      __syncthreads();                     // A
      chunkPV(i & 1);                      // PV(i)
      sstore_k(i & 1, kreg);
      sstore_v((i + 1) & 1, vreg);
      __syncthreads();                     // B
    }
    {   // i = 126
      bfx8 vreg[4];
      sload_v(127, vreg);
      pfload();                            // P(126)
      __syncthreads();                     // A
      chunkPV(0);
      sstore_v(1, vreg);
      __syncthreads();                     // B
    }
    // i = 127
    pfload();                              // P(127)
    __syncthreads();                       // C
    chunkPV(1);
    __syncthreads();                       // D: tot/ps ready

    // epilogue: normalize + self term, write concat rows mw..mw+31, full d
#pragma unroll
    for (int r = 0; r < 16; r++) {
      int row = (r & 3) + 8 * (r >> 2) + 4 * h;     // C/D layout row
      float dinv = 1.f / ex[grp * 32 + row];
      float ps   = ex[64 + grp * 32 + row];
      const __bf16* mvrow = mv + mbase + (long)row * 256;
      __bf16* crow = concat + ((long)(b * 1024 + mw + row)) * 2048 + hh * 256;
#pragma unroll
      for (int dt = 0; dt < 8; dt++) {
        int d = dt * 32 + l31;
        crow[d] = (__bf16)((oacc[dt][r] + ps * (float)mvrow[d]) * dinv);
      }
    }
  }
}

// ---------------- fallback: 256-thread r9 attention (proven 207 us) --------
// grid (SM/128, B, H) = 256 blocks, 4 waves; wave w owns Q rows w*32..w*32+31.
// K double-buffered two ahead, V one ahead; single barrier per chunk.
__global__ __launch_bounds__(256)
void attn_kernel_f(const __bf16* __restrict__ qb, const __bf16* __restrict__ ik,
                   const __bf16* __restrict__ ivT, const __bf16* __restrict__ mk,
                   const __bf16* __restrict__ mv, __bf16* __restrict__ concat) {
  __shared__ __bf16 lk[2][32][264];
  __shared__ __bf16 lvt[2][256][40];

  const int tid  = threadIdx.x;
  const int lane = tid & 63;
  const int w    = tid >> 6;
  const int l31  = lane & 31;
  const int h    = lane >> 5;

  const int m0 = blockIdx.x * 128;
  const int b  = blockIdx.y;
  const int hh = blockIdx.z;
  const int mw = m0 + w * 32;

  const long qbase  = ((long)hh * 4096 + b * 1024 + mw) * 256;
  const long kvbase = (long)b * 4096 * 256;
  const long vtbase = (long)b * 128 * 8192;
  const long mbase  = ((long)b * 1024 + mw) * 256;

  bfx8 qf[16];
  {
    const __bf16* qrow = qb + qbase + (long)l31 * 256 + h * 8;
#pragma unroll
    for (int kt = 0; kt < 16; kt++) qf[kt] = *(const bfx8*)(qrow + kt * 16);
  }

  float ps_l;
  {
    const __bf16* krow = mk + mbase + (long)l31 * 256 + h * 8;
    float s = 0.f;
#pragma unroll
    for (int kt = 0; kt < 16; kt++) {
      bfx8 kv = *(const bfx8*)(krow + kt * 16);
#pragma unroll
      for (int j = 0; j < 8; j++) s += (float)qf[kt][j] * (float)kv[j];
    }
    s += __shfl_xor(s, 32);
    ps_l = __builtin_amdgcn_exp2f(fminf(s * PSCALE, PCLAMP));
  }

  f32x16 oacc[8];
#pragma unroll
  for (int dt = 0; dt < 8; dt++)
#pragma unroll
    for (int i = 0; i < 16; i++) oacc[dt][i] = 0.f;
  float den_l = 0.f;
  bfx8 pf0c, pf1c;

  f32x16 zz;
#pragma unroll
  for (int i = 0; i < 16; i++) zz[i] = 0.f;

  auto sload_k = [&](int c, bfx8* kreg) {
    const long kb = kvbase + (long)c * 8192;
#pragma unroll
    for (int rep = 0; rep < 4; rep++) {
      int idx = rep * 256 + tid;
      kreg[rep] = *(const bfx8*)(ik + kb + (long)(idx >> 5) * 256 + (idx & 31) * 8);
    }
  };
  auto sload_v = [&](int c, bfx8* vreg) {
    const long vb = vtbase + (long)c * 8192;
#pragma unroll
    for (int rep = 0; rep < 4; rep++) {
      int idx = rep * 256 + tid;
      vreg[rep] = *(const bfx8*)(ivT + vb + (long)idx * 8);
    }
  };
  auto sstore_k = [&](int slot, const bfx8* kreg) {
#pragma unroll
    for (int rep = 0; rep < 4; rep++) {
      int idx = rep * 256 + tid;
      *(bfx8*)&lk[slot][idx >> 5][(idx & 31) * 8] = kreg[rep];
    }
  };
  auto sstore_v = [&](int slot, const bfx8* vreg) {
#pragma unroll
    for (int rep = 0; rep < 4; rep++) {
      int idx = rep * 256 + tid;
      *(bfx8*)&lvt[slot][idx >> 2][(idx & 3) * 8] = vreg[rep];
    }
  };

  auto chunkMFMA = [&](int vslot, int kslot, bool doS, bool doPV, f32x16* sa) {
#pragma unroll
    for (int t = 0; t < 8; t++) {
      bfx8 vf0, vf1, kf0, kf1;
      if (doPV) {
        vf0 = *(const bfx8*)&lvt[vslot][t * 32 + l31][h * 8];
        vf1 = *(const bfx8*)&lvt[vslot][t * 32 + l31][16 + h * 8];
      }
      if (doS) {
        kf0 = *(const bfx8*)&lk[kslot][l31][(2 * t) * 16 + h * 8];
        kf1 = *(const bfx8*)&lk[kslot][l31][(2 * t + 1) * 16 + h * 8];
      }
      if (doPV) oacc[t] = MFMA32(pf0c, vf0, oacc[t]);
      if (doS) {
        if (t < 2) sa[2 * t] = MFMA32(kf0, qf[2 * t], zz);
        else       sa[(2 * t) & 3] = MFMA32(kf0, qf[2 * t], sa[(2 * t) & 3]);
      }
      if (doPV) oacc[t] = MFMA32(pf1c, vf1, oacc[t]);
      if (doS) {
        if (t < 2) sa[2 * t + 1] = MFMA32(kf1, qf[2 * t + 1], zz);
        else       sa[(2 * t + 1) & 3] = MFMA32(kf1, qf[2 * t + 1], sa[(2 * t + 1) & 3]);
      }
    }
  };

  auto finishP = [&](const f32x16* sa) {
    float p[16];
#pragma unroll
    for (int r = 0; r < 16; r++) {
      float s = (sa[0][r] + sa[1][r]) + (sa[2][r] + sa[3][r]);
      p[r] = __builtin_amdgcn_exp2f(fminf(s * PSCALE, PCLAMP));
      den_l += p[r];
    }
    pf0c = packswap(p);
    pf1c = packswap(p + 8);
  };

  {
    bfx8 kreg[4], vreg[4];
    sload_k(0, kreg);
    sload_v(0, vreg);
    sstore_k(0, kreg);
    sstore_v(0, vreg);
    sload_k(1, kreg);
    sstore_k(1, kreg);
  }
  __syncthreads();

  f32x16 sa[4];
  chunkMFMA(0, 0, true, false, sa);
  finishP(sa);
  __syncthreads();

  for (int i = 0; i < 126; i++) {
    bfx8 kreg[4], vreg[4];
    sload_k(i + 2, kreg);
    sload_v(i + 1, vreg);
    chunkMFMA(i & 1, (i + 1) & 1, true, true, sa);
    sstore_k(i & 1, kreg);
    sstore_v((i + 1) & 1, vreg);
    finishP(sa);
    __syncthreads();
  }
  {
    bfx8 vreg[4];
    sload_v(127, vreg);
    chunkMFMA(0, 1, true, true, sa);
    sstore_v(1, vreg);
    finishP(sa);
    __syncthreads();
  }
  chunkMFMA(1, 0, false, true, sa);

  float tot = den_l + __shfl_xor(den_l, 32) + ps_l;
#pragma unroll
  for (int r = 0; r < 16; r++) {
    int row = (r & 3) + 8 * (r >> 2) + 4 * h;
    float ps   = __shfl(ps_l, row);
    float dinv = 1.f / __shfl(tot, row);
    const __bf16* mvrow = mv + mbase + (long)row * 256;
    __bf16* crow = concat + ((long)(b * 1024 + mw + row)) * 2048 + hh * 256;
#pragma unroll
    for (int dt = 0; dt < 8; dt++) {
      int d = dt * 32 + l31;
      crow[d] = (__bf16)((oacc[dt][r] + ps * (float)mvrow[d]) * dinv);
    }
  }
}

// ---------------- LayerNorm over 4 f32 partials + residual ----------------
__global__ __launch_bounds__(256)
void ln4_kernel(const float* __restrict__ parts, const float* __restrict__ res,
                const float* __restrict__ g, const float* __restrict__ beta,
                __bf16* __restrict__ outb, float* __restrict__ outf) {
  int row  = blockIdx.x * 4 + (threadIdx.x >> 6);
  int lane = threadIdx.x & 63;
  const float* p = parts + (long)row * 256 + lane * 4;
  f32x4 a0 = *(const f32x4*)p;
  f32x4 a1 = *(const f32x4*)(p + 1048576);
  f32x4 a2 = *(const f32x4*)(p + 2097152);
  f32x4 a3 = *(const f32x4*)(p + 3145728);
  f32x4 rv = *(const f32x4*)(res + (long)row * 256 + lane * 4);
  float v[4], s1 = 0.f, s2 = 0.f;
#pragma unroll
  for (int i = 0; i < 4; i++) {
    v[i] = a0[i] + a1[i] + a2[i] + a3[i] + rv[i];
    s1 += v[i];
    s2 += v[i] * v[i];
  }
#pragma unroll
  for (int off = 32; off >= 1; off >>= 1) {
    s1 += __shfl_xor(s1, off);
    s2 += __shfl_xor(s2, off);
  }
  float mean = s1 * (1.f / 256.f);
  float var  = fmaxf(s2 * (1.f / 256.f) - mean * mean, 0.f);
  float rstd = rsqrtf(var + 1e-6f);
#pragma unroll
  for (int i = 0; i < 4; i++) {
    int c = lane * 4 + i;
    float o = (v[i] - mean) * rstd * g[c] + beta[c];
    if (outb) outb[(long)row * 256 + c] = (__bf16)o;
    if (outf) outf[(long)row * 256 + c] = o;
  }
}

extern "C" void kernel_launch(void* const* d_in, const int* in_sizes, int n_in,
                              void* d_out, int out_size, void* d_ws, size_t ws_size,
                              hipStream_t stream) {
  const float* state  = (const float*)d_in[0];
  const float* input  = (const float*)d_in[1];
  const float* Wk     = (const float*)d_in[2];
  const float* bk     = (const float*)d_in[3];
  const float* Wv     = (const float*)d_in[4];
  const float* bv     = (const float*)d_in[5];
  const float* Wq     = (const float*)d_in[6];
  const float* bq     = (const float*)d_in[7];
  const float* Wo     = (const float*)d_in[8];
  const float* bo     = (const float*)d_in[9];
  const float* ln1g   = (const float*)d_in[10];
  const float* ln1b   = (const float*)d_in[11];
  const float* W_in   = (const float*)d_in[12];
  const float* b_in   = (const float*)d_in[13];
  const float* Wg_nl  = (const float*)d_in[14];
  const float* bg_nl  = (const float*)d_in[15];
  const float* Wg_l   = (const float*)d_in[16];
  const float* bg_l   = (const float*)d_in[17];
  const float* Wg_o   = (const float*)d_in[18];
  const float* bg_o   = (const float*)d_in[19];
  const float* ln2g   = (const float*)d_in[20];
  const float* ln2b   = (const float*)d_in[21];
  float* out = (float*)d_out;

  const size_t needed_elems = 28442624;   // 56.9 MB, proven budget
  if (ws_size < needed_elems * sizeof(__bf16)) return;

  __bf16* ws = (__bf16*)d_ws;
  size_t off = 0;
  auto alloc = [&](size_t n) { __bf16* p = ws + off; off += n; return p; };
  __bf16* Wkvqt  = alloc(655360);    // [2560][256]: Wk^T | Wv^T | Wq^T(8)
  __bf16* Wot    = alloc(524288);    // [256][2048]
  __bf16* ik     = alloc(4194304);   // [16384][256]
  __bf16* ivT    = alloc(4194304);   // [4][128][256][32]
  __bf16* mk     = alloc(1048576);   // [4096][256]
  __bf16* mv     = alloc(1048576);
  __bf16* qbuf   = alloc(8388608);   // [8][4096][256]
  __bf16* concat = alloc(8388608);   // [4096][2048]
  // FFN/late-phase aliases over dead buffers
  float*  wo_parts = (float*)qbuf;           // f32[4][4096][256] (qbuf dead after attn)
  __bf16* x      = mv;                       // bf16 LN1 out
  __bf16* hbuf   = ik;                       // [4096][1024]
  __bf16* t12    = qbuf;                     // [4096][2048]
  float*  ff_parts = (float*)ik;             // f32[4][4096][256] over ik+ivT
  __bf16* Wffn   = concat;                   // FFN weights^T (2621440 el)
  float*  xf     = (float*)(concat + 3670016); // f32 residual [4096][256]

  // codegen hedge (r10-r14 lesson): use the role-split kernel only if it
  // compiled without scratch spills; else fall back to the proven r9 kernel.
  static int useS = -1;
  if (useS < 0) {
    hipFuncAttributes fa{};
    hipError_t e = hipFuncGetAttributes(&fa, (const void*)attn_kernel_s);
    useS = (e == hipSuccess && fa.localSizeBytes <= 16) ? 1 : 0;
  }

  dim3 blk(256);

  trans_attn_t<<<dim3(288), blk, 0, stream>>>(Wk, Wv, Wq, Wo, Wkvqt, Wot);

  // merged projections: K|V input (512 blocks) + K|V|Q state (640 blocks)
  proj2<<<dim3(1152), blk, 0, stream>>>(input, state, Wkvqt, bk, bv, bq,
                                        ik, ivT, mk, mv, qbuf);

  if (useS)
    attn_kernel_s<<<dim3(16, 4, 8), blk, 0, stream>>>(qbuf, ik, ivT, mk, mv, concat);
  else
    attn_kernel_f<<<dim3(8, 4, 8), blk, 0, stream>>>(qbuf, ik, ivT, mk, mv, concat);

  // Wo: split-K (4 x 512) -> f32 partials, 256 blocks
  gemm_bt<<<dim3(32, 2, 4), blk, 0, stream>>>(concat, nullptr, Wot, bo, nullptr, nullptr,
                                              nullptr, nullptr, nullptr, wo_parts,
                                              4096, 256, 2048, 512, 0, 7, 0);
  ln4_kernel<<<dim3(1024), blk, 0, stream>>>(wo_parts, state, ln1g, ln1b, x, xf);

  trans_ffn_t<<<dim3(640), blk, 0, stream>>>(W_in, Wg_nl, Wg_l, Wg_o, Wffn);

  gemm_bt<<<dim3(32, 8), blk, 0, stream>>>(x, nullptr, Wffn, b_in, nullptr, nullptr,
                                           hbuf, nullptr, nullptr, nullptr,
                                           4096, 1024, 256, 256, 0, 0, 1);
  // fused Wg_nl|Wg_l: N=2048, relu on first half
  gemm_bt<<<dim3(32, 16), blk, 0, stream>>>(hbuf, nullptr, Wffn + 262144, bg_nl, bg_l, nullptr,
                                            t12, nullptr, nullptr, nullptr,
                                            4096, 2048, 1024, 1024, 0, 6, 0);
  // Wg_o with gating fused into the stager: split-K (4 x 256) -> f32 partials
  gemm_bt<<<dim3(32, 2, 4), blk, 0, stream>>>(t12, nullptr, Wffn + 2359296, bg_o, nullptr, nullptr,
                                              nullptr, nullptr, nullptr, ff_parts,
                                              4096, 256, 1024, 256, 2, 7, 0);
  ln4_kernel<<<dim3(1024), blk, 0, stream>>>(ff_parts, xf, ln2g, ln2b, nullptr, out);
}

// Round 9
// 450.143 us; speedup vs baseline: 1.0884x; 1.0884x over previous
//
#include <hip/hip_runtime.h>
#include <hip/hip_bf16.h>

typedef __bf16 bfx8 __attribute__((ext_vector_type(8)));
typedef __bf16 bfx4 __attribute__((ext_vector_type(4)));
typedef float  f32x4 __attribute__((ext_vector_type(4)));
typedef float  f32x16 __attribute__((ext_vector_type(16)));

#define MFMA16(a,b,c) __builtin_amdgcn_mfma_f32_16x16x32_bf16((a),(b),(c),0,0,0)
#define MFMA32(a,b,c) __builtin_amdgcn_mfma_f32_32x32x16_bf16((a),(b),(c),0,0,0)

// B=4, SM=1024, SI=4096, D=256, H=8, FF=1024
// External I/O: float32. Internal: bf16 operands + f32 accumulation.

// exp(min(s*0.0625, 30)) == exp2(min(s*0.0625*log2e, 30*log2e))
// (__expf lowers to mul(log2e)+v_exp; folding removes one dependent mul)
#define PSCALE 0.09016844f
#define PCLAMP 43.2808512f

__device__ __forceinline__ unsigned cvtpk_bf16(float lo, float hi) {
  unsigned d;
  asm("v_cvt_pk_bf16_f32 %0, %1, %2" : "=v"(d) : "v"(lo), "v"(hi));
  return d;
}

// Assemble one P A-fragment (bfx8, k = h*8+j) from 8 per-lane probabilities.
// After swapped QK^T (S^T), lane (l31,h) holds P[q=l31][key=(r&3)+8*(r>>2)+4h].
// cvt_pk pairs + two permlane32_swap (hi<->lo half exchange) complete the
// in-register transpose slice — replaces the LDS round trip.
__device__ __forceinline__ bfx8 packswap(const float* p) {
  unsigned a = cvtpk_bf16(p[0], p[1]);
  unsigned b = cvtpk_bf16(p[2], p[3]);
  unsigned c = cvtpk_bf16(p[4], p[5]);
  unsigned d = cvtpk_bf16(p[6], p[7]);
  asm("v_permlane32_swap_b32 %0, %1" : "+v"(a), "+v"(c));
  asm("v_permlane32_swap_b32 %0, %1" : "+v"(b), "+v"(d));
  union { unsigned u[4]; bfx8 v; } uu;
  uu.u[0] = a; uu.u[1] = b; uu.u[2] = c; uu.u[3] = d;
  return uu.v;
}

// ---------------- coalesced 64x64 tile transpose (f32 -> bf16^T) ----------------
__device__ __forceinline__ void tile_tr(const float* __restrict__ src, __bf16* __restrict__ dst,
                                        int R, int C, int tile, float (*lt)[65]) {
  int tpr = C >> 6;
  int tr = tile / tpr, tc = tile % tpr;
  int c  = threadIdx.x & 63;
  int r0 = (threadIdx.x >> 6) << 4;
  const float* sp = src + (long)(tr * 64 + r0) * C + tc * 64 + c;
#pragma unroll
  for (int i = 0; i < 16; i++) lt[r0 + i][c] = sp[(long)i * C];
  __syncthreads();
  __bf16* dp = dst + (long)(tc * 64 + r0) * R + tr * 64 + c;
#pragma unroll
  for (int i = 0; i < 16; i++) dp[(long)i * R] = (__bf16)lt[c][r0 + i];
}

__global__ void trans_attn_t(const float* __restrict__ Wk, const float* __restrict__ Wv,
                             const float* __restrict__ Wq, const float* __restrict__ Wo,
                             __bf16* __restrict__ wkvqt, __bf16* __restrict__ wot) {
  __shared__ float lt[64][65];
  int t = blockIdx.x;
  if (t < 16)       tile_tr(Wk, wkvqt, 256, 256, t, lt);
  else if (t < 32)  tile_tr(Wv, wkvqt + 65536, 256, 256, t - 16, lt);
  else if (t < 160) {
    int e = t - 32, m = e >> 4;
    tile_tr(Wq + (long)m * 65536, wkvqt + 131072 + (long)m * 65536, 256, 256, e & 15, lt);
  } else            tile_tr(Wo, wot, 2048, 256, t - 160, lt);
}

// ---------------- GEMM body: C[M,N] = act(X[M,K] @ Wt[N,K]^T + bias) ----------------
// xmode: 0 bf16 X (row stride Kfull); 1 f32 X; 2 gated bf16 (stride 2048, x=a*b pairs k,k+1024)
// mode: 0 plain; 4 K|V split; 5 K|V|Q split; 6 dual-act (relu iff n<1024);
//       7 split-K f32 partials: Cf[z*M*N + m*N + n] (bias added in z==0 slice)
__device__ __forceinline__
void gemm_body(const __bf16* __restrict__ Xb, const float* __restrict__ Xf,
               const __bf16* __restrict__ Wt,
               const float* __restrict__ b1, const float* __restrict__ b2,
               const float* __restrict__ b3,
               __bf16* __restrict__ C, __bf16* __restrict__ C2, __bf16* __restrict__ C3,
               float* __restrict__ Cf,
               int M, int N, int Kfull, int kspan, int xmode, int mode, int act,
               int bx, int by, int bz, __bf16* xs, __bf16* wsm) {
  const int tid  = threadIdx.x;
  const int lane = tid & 63;
  const int w    = tid >> 6;
  const int l15  = lane & 15;
  const int quad = lane >> 4;
  const int wm   = (w >> 1) * 64;
  const int wn   = (w & 1) * 64;
  const int m0   = bx * 128;
  const int n0   = by * 128;
  const int k0   = (mode == 7) ? bz * kspan : 0;

  f32x4 acc[4][4];
#pragma unroll
  for (int i = 0; i < 4; i++)
#pragma unroll
    for (int j = 0; j < 4; j++) acc[i][j] = (f32x4){0.f, 0.f, 0.f, 0.f};

  for (int kk = k0; kk < k0 + kspan; kk += 64) {
    __syncthreads();
#pragma unroll
    for (int rep = 0; rep < 4; rep++) {
      int idx = rep * 256 + tid;
      int row = idx >> 3;
      int g   = idx & 7;
      if (xmode == 1) {
        const float* p = Xf + (long)(m0 + row) * Kfull + kk + g * 8;
        f32x4 a0 = *(const f32x4*)p;
        f32x4 a1 = *(const f32x4*)(p + 4);
        bfx8 v;
#pragma unroll
        for (int j = 0; j < 4; j++) { v[j] = (__bf16)a0[j]; v[4 + j] = (__bf16)a1[j]; }
        *(bfx8*)&xs[row * 72 + g * 8] = v;
      } else if (xmode == 2) {
        const __bf16* p = Xb + (long)(m0 + row) * 2048 + kk + g * 8;
        bfx8 a = *(const bfx8*)p;
        bfx8 bb = *(const bfx8*)(p + 1024);
        bfx8 v;
#pragma unroll
        for (int j = 0; j < 8; j++) v[j] = (__bf16)((float)a[j] * (float)bb[j]);
        *(bfx8*)&xs[row * 72 + g * 8] = v;
      } else {
        *(bfx8*)&xs[row * 72 + g * 8] = *(const bfx8*)(Xb + (long)(m0 + row) * Kfull + kk + g * 8);
      }
      *(bfx8*)&wsm[row * 72 + g * 8] = *(const bfx8*)(Wt + (long)(n0 + row) * Kfull + kk + g * 8);
    }
    __syncthreads();
#pragma unroll
    for (int ks = 0; ks < 2; ks++) {
      bfx8 af[4], bf_[4];
#pragma unroll
      for (int i = 0; i < 4; i++) af[i]  = *(const bfx8*)&xs[(wm + 16 * i + l15) * 72 + ks * 32 + quad * 8];
#pragma unroll
      for (int j = 0; j < 4; j++) bf_[j] = *(const bfx8*)&wsm[(wn + 16 * j + l15) * 72 + ks * 32 + quad * 8];
#pragma unroll
      for (int i = 0; i < 4; i++)
#pragma unroll
        for (int j = 0; j < 4; j++) acc[i][j] = MFMA16(af[i], bf_[j], acc[i][j]);
    }
  }

#pragma unroll
  for (int j = 0; j < 4; j++) {
    int n = n0 + wn + 16 * j + l15;
    float bv;
    if (mode == 4)      bv = (n < 256) ? b1[n] : b2[n - 256];
    else if (mode == 5) bv = (n < 256) ? b1[n] : (n < 512) ? b2[n - 256] : b3[n - 512];
    else if (mode == 6) bv = (n < 1024) ? b1[n] : b2[n - 1024];
    else if (mode == 7) bv = (bz == 0) ? b1[n] : 0.f;
    else                bv = b1[n];
#pragma unroll
    for (int i = 0; i < 4; i++) {
#pragma unroll
      for (int r = 0; r < 4; r++) {
        int m = m0 + wm + 16 * i + quad * 4 + r;   // C/D layout: row = quad*4+reg
        float v = acc[i][j][r] + bv;
        if (mode == 6) { if (n < 1024) v = fmaxf(v, 0.f); }
        else if (act == 1) v = fmaxf(v, 0.f);
        if (mode == 4) {
          if (n < 256) C[(long)m * 256 + n] = (__bf16)v;
          else {
            int bb_ = m >> 12, si = m & 4095;
            C2[((long)(bb_ * 128 + (si >> 5)) * 256 + (n - 256)) * 32 + (si & 31)] = (__bf16)v;
          }
        } else if (mode == 5) {
          if (n < 256)      C[(long)m * 256 + n] = (__bf16)v;
          else if (n < 512) C2[(long)m * 256 + (n - 256)] = (__bf16)v;
          else {
            int nn = n - 512, hhh = nn >> 8, dd = nn & 255;
            C3[(long)hhh * 1048576 + (long)m * 256 + dd] = (__bf16)v;
          }
        } else if (mode == 7) {
          Cf[(long)bz * M * N + (long)m * N + n] = v;
        } else {
          C[(long)m * N + n] = (__bf16)v;
        }
      }
    }
  }
}

__global__ __launch_bounds__(256)
void gemm_bt(const __bf16* Xb, const float* Xf, const __bf16* Wt,
             const float* b1, const float* b2, const float* b3,
             __bf16* C, __bf16* C2, __bf16* C3, float* Cf,
             int M, int N, int Kfull, int kspan, int xmode, int mode, int act) {
  __shared__ __bf16 xs[128 * 72];
  __shared__ __bf16 wsm[128 * 72];
  gemm_body(Xb, Xf, Wt, b1, b2, b3, C, C2, C3, Cf, M, N, Kfull, kspan, xmode, mode, act,
            blockIdx.x, blockIdx.y, blockIdx.z, xs, wsm);
}

// merged K|V input projection (blocks 0..511, grid (128,4)) + K|V|Q state projection
// (blocks 512..1151, grid (32,20)) — both depend only on trans_attn_t.
__global__ __launch_bounds__(256)
void proj2(const float* input, const float* state, const __bf16* Wkvqt,
           const float* bk, const float* bv, const float* bq,
           __bf16* ik, __bf16* ivT, __bf16* mk, __bf16* mv, __bf16* qbuf) {
  __shared__ __bf16 xs[128 * 72];
  __shared__ __bf16 wsm[128 * 72];
  int bid = blockIdx.x;
  if (bid < 512) {
    gemm_body(nullptr, input, Wkvqt, bk, bv, nullptr, ik, ivT, nullptr, nullptr,
              16384, 512, 256, 256, 1, 4, 0, bid & 127, bid >> 7, 0, xs, wsm);
  } else {
    int b2 = bid - 512;
    gemm_body(nullptr, state, Wkvqt, bk, bv, bq, mk, mv, qbuf, nullptr,
              4096, 2560, 256, 256, 1, 5, 0, b2 & 31, b2 >> 5, 0, xs, wsm);
  }
}

// ---------------- fused multi-query attention (r16 = r8 datapath + exp2) --------
// PROVEN BEST (R1: 204 us attn, 451.6 us total). grid (SM/128, B, H) = 256
// blocks, 4 waves; wave w owns Q rows w*32..w*32+31.
// Swapped QK^T (S^T via MFMA32(K,Q)) -> P-row lane-local -> in-register
// P->A-frag via cvt_pk_bf16 + permlane32_swap (no LDS round trip).
// S(c+1) interleaved with PV(c) in one MFMA block; 4-way split S accumulators.
// K double-buffered, V triple-buffered => ONE barrier per chunk race-free:
//   iter i: reads lvt[i%3], lk[(i+1)&1]; writes lk[i&1], lvt[(i+2)%3].
// Post-R8 ledger: 4 structural attempts at 2 waves/SIMD (8-wave block r10-r12:
// backend pins 128 VGPR; d-split r13/r14: occupancy 20% but 1.5x duplicated S;
// role-split r15: no dup but 2 barriers + 2x staging) all landed 229-399 us.
// The register wall (oacc128+sa64+qf64 acc regs/wave) blocks a no-duplication
// 2/SIMD layout; this 1-wave/SIMD structure remains the measured optimum.
__global__ __launch_bounds__(256)
void attn_kernel(const __bf16* __restrict__ qb,   // [H][B*SM][256]
                 const __bf16* __restrict__ ik,   // [B*SI][256]
                 const __bf16* __restrict__ ivT,  // [B][128][256][32]
                 const __bf16* __restrict__ mk,   // [B*SM][256]
                 const __bf16* __restrict__ mv,   // [B*SM][256]
                 __bf16* __restrict__ concat) {   // [B*SM][2048]
  __shared__ __bf16 lk[2][32][264];     // K chunks [buf][key][d], +8 pad   (33.8 KB)
  __shared__ __bf16 lvt[3][256][40];    // V^T chunks [buf][d][key], +8 pad (61.4 KB)

  const int tid  = threadIdx.x;
  const int lane = tid & 63;
  const int w    = tid >> 6;
  const int l31  = lane & 31;
  const int h    = lane >> 5;

  const int m0 = blockIdx.x * 128;
  const int b  = blockIdx.y;
  const int hh = blockIdx.z;
  const int mw = m0 + w * 32;

  const long qbase  = ((long)hh * 4096 + b * 1024 + mw) * 256;
  const long kvbase = (long)b * 4096 * 256;
  const long vtbase = (long)b * 128 * 8192;
  const long mbase  = ((long)b * 1024 + mw) * 256;

  // Q frags: lane holds Q[q=l31][d = kt*16 + h*8 + j] (A- and B-layout identical)
  bfx8 qf[16];
  {
    const __bf16* qrow = qb + qbase + (long)l31 * 256 + h * 8;
#pragma unroll
    for (int kt = 0; kt < 16; kt++) qf[kt] = *(const bfx8*)(qrow + kt * 16);
  }

  // self score for row l31 (halves hold complementary d-slices; xor-32 combines)
  float ps_l;
  {
    const __bf16* krow = mk + mbase + (long)l31 * 256 + h * 8;
    float s = 0.f;
#pragma unroll
    for (int kt = 0; kt < 16; kt++) {
      bfx8 kv = *(const bfx8*)(krow + kt * 16);
#pragma unroll
      for (int j = 0; j < 8; j++) s += (float)qf[kt][j] * (float)kv[j];
    }
    s += __shfl_xor(s, 32);
    ps_l = __builtin_amdgcn_exp2f(fminf(s * PSCALE, PCLAMP));
  }

  f32x16 oacc[8];
#pragma unroll
  for (int dt = 0; dt < 8; dt++)
#pragma unroll
    for (int i = 0; i < 16; i++) oacc[dt][i] = 0.f;
  float den_l = 0.f;          // per-lane partial denominator (own 16 keys/chunk)
  bfx8 pf0c, pf1c;            // current P A-frags (keys 0-15 / 16-31)

  f32x16 zz;
#pragma unroll
  for (int i = 0; i < 16; i++) zz[i] = 0.f;

  auto sload = [&](int c, bfx8* kreg, bfx8* vreg) {
    const long kb = kvbase + (long)c * 8192;
    const long vb = vtbase + (long)c * 8192;
#pragma unroll
    for (int rep = 0; rep < 4; rep++) {
      int idx = rep * 256 + tid;
      kreg[rep] = *(const bfx8*)(ik + kb + (long)(idx >> 5) * 256 + (idx & 31) * 8);
      vreg[rep] = *(const bfx8*)(ivT + vb + (long)idx * 8);
    }
  };
  auto sstore = [&](int kslot, int vslot, const bfx8* kreg, const bfx8* vreg) {
#pragma unroll
    for (int rep = 0; rep < 4; rep++) {
      int idx = rep * 256 + tid;
      *(bfx8*)&lk[kslot][idx >> 5][(idx & 31) * 8] = kreg[rep];
      *(bfx8*)&lvt[vslot][idx >> 2][(idx & 3) * 8] = vreg[rep];
    }
  };

  // Interleaved MFMA block: PV(cur chunk) from lvt[vslot] + S^T(next chunk)
  // from lk[kslot]. sa[4] = split S accumulators (dep chains of 4).
  auto chunkMFMA = [&](int vslot, int kslot, bool doS, bool doPV, f32x16* sa) {
#pragma unroll
    for (int t = 0; t < 8; t++) {
      bfx8 vf0, vf1, kf0, kf1;
      if (doPV) {
        vf0 = *(const bfx8*)&lvt[vslot][t * 32 + l31][h * 8];
        vf1 = *(const bfx8*)&lvt[vslot][t * 32 + l31][16 + h * 8];
      }
      if (doS) {
        kf0 = *(const bfx8*)&lk[kslot][l31][(2 * t) * 16 + h * 8];
        kf1 = *(const bfx8*)&lk[kslot][l31][(2 * t + 1) * 16 + h * 8];
      }
      if (doPV) oacc[t] = MFMA32(pf0c, vf0, oacc[t]);
      if (doS) {
        if (t < 2) sa[2 * t] = MFMA32(kf0, qf[2 * t], zz);
        else       sa[(2 * t) & 3] = MFMA32(kf0, qf[2 * t], sa[(2 * t) & 3]);
      }
      if (doPV) oacc[t] = MFMA32(pf1c, vf1, oacc[t]);
      if (doS) {
        if (t < 2) sa[2 * t + 1] = MFMA32(kf1, qf[2 * t + 1], zz);
        else       sa[(2 * t + 1) & 3] = MFMA32(kf1, qf[2 * t + 1], sa[(2 * t + 1) & 3]);
      }
    }
  };

  // exp + in-register transpose -> next chunk's P A-frags
  auto finishP = [&](const f32x16* sa) {
    float p[16];
#pragma unroll
    for (int r = 0; r < 16; r++) {
      float s = (sa[0][r] + sa[1][r]) + (sa[2][r] + sa[3][r]);
      p[r] = __builtin_amdgcn_exp2f(fminf(s * PSCALE, PCLAMP));
      den_l += p[r];
    }
    pf0c = packswap(p);
    pf1c = packswap(p + 8);
  };

  // prologue: stage chunks 0,1
  {
    bfx8 kreg[4], vreg[4];
    sload(0, kreg, vreg);
    sstore(0, 0, kreg, vreg);
    sload(1, kreg, vreg);
    sstore(1, 1, kreg, vreg);
  }
  __syncthreads();

  f32x16 sa[4];
  chunkMFMA(0, 0, true, false, sa);   // S(0) from lk[0]
  finishP(sa);                        // -> P(0)
  __syncthreads();                    // protect lk[0] before iter-0 overwrite

  int vcur = 0, vnst = 2;
  for (int i = 0; i < 126; i++) {
    bfx8 kreg[4], vreg[4];
    sload(i + 2, kreg, vreg);                    // issue early, consumed at sstore
    chunkMFMA(vcur, (i + 1) & 1, true, true, sa); // PV(i) || S(i+1)
    sstore(i & 1, vnst, kreg, vreg);             // K(i+2)->lk[i&1], V(i+2)->lvt[vnst]
    finishP(sa);                                 // -> P(i+1), overlaps ds_write drain
    __syncthreads();
    vcur = (vcur == 2) ? 0 : vcur + 1;
    vnst = (vnst == 2) ? 0 : vnst + 1;
  }
  // i = 126: PV(126) [lvt[0]] || S(127) [lk[1]]; no staging
  chunkMFMA(0, 1, true, true, sa);
  finishP(sa);                                   // -> P(127)
  // tail: PV(127) from lvt[1]
  chunkMFMA(1, 0, false, true, sa);

  // epilogue: combine denominator halves + self term, normalize, scatter
  float tot = den_l + __shfl_xor(den_l, 32) + ps_l;  // lane l31 holds row-l31 total
#pragma unroll
  for (int r = 0; r < 16; r++) {
    int row = (r & 3) + 8 * (r >> 2) + 4 * h;   // C/D layout row
    float ps   = __shfl(ps_l, row);
    float dinv = 1.f / __shfl(tot, row);
    const __bf16* mvrow = mv + mbase + (long)row * 256;
    __bf16* crow = concat + ((long)(b * 1024 + mw + row)) * 2048 + hh * 256;
#pragma unroll
    for (int dt = 0; dt < 8; dt++) {
      int d = dt * 32 + l31;
      crow[d] = (__bf16)((oacc[dt][r] + ps * (float)mvrow[d]) * dinv);
    }
  }
}

// ---------------- LayerNorm over 4 f32 partials + residual (device body) ------
__device__ __forceinline__
void ln4_body(const float* __restrict__ parts, const float* __restrict__ res,
              const float* __restrict__ g, const float* __restrict__ beta,
              __bf16* __restrict__ outb, float* __restrict__ outf, int bid) {
  int row  = bid * 4 + (threadIdx.x >> 6);
  int lane = threadIdx.x & 63;
  const float* p = parts + (long)row * 256 + lane * 4;
  f32x4 a0 = *(const f32x4*)p;
  f32x4 a1 = *(const f32x4*)(p + 1048576);
  f32x4 a2 = *(const f32x4*)(p + 2097152);
  f32x4 a3 = *(const f32x4*)(p + 3145728);
  f32x4 rv = *(const f32x4*)(res + (long)row * 256 + lane * 4);
  float v[4], s1 = 0.f, s2 = 0.f;
#pragma unroll
  for (int i = 0; i < 4; i++) {
    v[i] = a0[i] + a1[i] + a2[i] + a3[i] + rv[i];
    s1 += v[i];
    s2 += v[i] * v[i];
  }
#pragma unroll
  for (int off = 32; off >= 1; off >>= 1) {
    s1 += __shfl_xor(s1, off);
    s2 += __shfl_xor(s2, off);
  }
  float mean = s1 * (1.f / 256.f);
  float var  = fmaxf(s2 * (1.f / 256.f) - mean * mean, 0.f);
  float rstd = rsqrtf(var + 1e-6f);
#pragma unroll
  for (int i = 0; i < 4; i++) {
    int c = lane * 4 + i;
    float o = (v[i] - mean) * rstd * g[c] + beta[c];
    if (outb) outb[(long)row * 256 + c] = (__bf16)o;
    if (outf) outf[(long)row * 256 + c] = o;
  }
}

__global__ __launch_bounds__(256)
void ln4_kernel(const float* __restrict__ parts, const float* __restrict__ res,
                const float* __restrict__ g, const float* __restrict__ beta,
                __bf16* __restrict__ outb, float* __restrict__ outf) {
  ln4_body(parts, res, g, beta, outb, outf, blockIdx.x);
}

// Merged launch: LN1 (blocks 0..1023) + FFN weight transpose (blocks 1024..1663).
// Independent work, disjoint buffers (xf at concat+7.34MB vs Wffn at concat+0..
// 5.24MB; attn's concat content already consumed by the Wo split-K gemm).
// Saves one inter-kernel gap on the serial stream.
__global__ __launch_bounds__(256)
void ln4_trffn(const float* __restrict__ parts, const float* __restrict__ res,
               const float* __restrict__ g, const float* __restrict__ beta,
               __bf16* __restrict__ outb, float* __restrict__ outf,
               const float* __restrict__ W_in, const float* __restrict__ Wg_nl,
               const float* __restrict__ Wg_l, const float* __restrict__ Wg_o,
               __bf16* __restrict__ wdst) {
  __shared__ float lt[64][65];
  int bid = blockIdx.x;
  if (bid < 1024) {
    ln4_body(parts, res, g, beta, outb, outf, bid);
  } else {
    int t = bid - 1024;
    if (t < 64)       tile_tr(W_in, wdst, 256, 1024, t, lt);
    else if (t < 320) tile_tr(Wg_nl, wdst + 262144, 1024, 1024, t - 64, lt);
    else if (t < 576) tile_tr(Wg_l, wdst + 1310720, 1024, 1024, t - 320, lt);
    else              tile_tr(Wg_o, wdst + 2359296, 1024, 256, t - 576, lt);
  }
}

extern "C" void kernel_launch(void* const* d_in, const int* in_sizes, int n_in,
                              void* d_out, int out_size, void* d_ws, size_t ws_size,
                              hipStream_t stream) {
  const float* state  = (const float*)d_in[0];
  const float* input  = (const float*)d_in[1];
  const float* Wk     = (const float*)d_in[2];
  const float* bk     = (const float*)d_in[3];
  const float* Wv     = (const float*)d_in[4];
  const float* bv     = (const float*)d_in[5];
  const float* Wq     = (const float*)d_in[6];
  const float* bq     = (const float*)d_in[7];
  const float* Wo     = (const float*)d_in[8];
  const float* bo     = (const float*)d_in[9];
  const float* ln1g   = (const float*)d_in[10];
  const float* ln1b   = (const float*)d_in[11];
  const float* W_in   = (const float*)d_in[12];
  const float* b_in   = (const float*)d_in[13];
  const float* Wg_nl  = (const float*)d_in[14];
  const float* bg_nl  = (const float*)d_in[15];
  const float* Wg_l   = (const float*)d_in[16];
  const float* bg_l   = (const float*)d_in[17];
  const float* Wg_o   = (const float*)d_in[18];
  const float* bg_o   = (const float*)d_in[19];
  const float* ln2g   = (const float*)d_in[20];
  const float* ln2b   = (const float*)d_in[21];
  float* out = (float*)d_out;

  const size_t needed_elems = 28442624;   // 56.9 MB, proven budget
  if (ws_size < needed_elems * sizeof(__bf16)) return;

  __bf16* ws = (__bf16*)d_ws;
  size_t off = 0;
  auto alloc = [&](size_t n) { __bf16* p = ws + off; off += n; return p; };
  __bf16* Wkvqt  = alloc(655360);    // [2560][256]: Wk^T | Wv^T | Wq^T(8)
  __bf16* Wot    = alloc(524288);    // [256][2048]
  __bf16* ik     = alloc(4194304);   // [16384][256]
  __bf16* ivT    = alloc(4194304);   // [4][128][256][32]
  __bf16* mk     = alloc(1048576);   // [4096][256]
  __bf16* mv     = alloc(1048576);
  __bf16* qbuf   = alloc(8388608);   // [8][4096][256]
  __bf16* concat = alloc(8388608);   // [4096][2048]
  // FFN/late-phase aliases over dead buffers
  float*  wo_parts = (float*)qbuf;           // f32[4][4096][256] (qbuf dead after attn)
  __bf16* x      = mv;                       // bf16 LN1 out
  __bf16* hbuf   = ik;                       // [4096][1024]
  __bf16* t12    = qbuf;                     // [4096][2048]
  float*  ff_parts = (float*)ik;             // f32[4][4096][256] over ik+ivT
  __bf16* Wffn   = concat;                   // FFN weights^T (2621440 el)
  float*  xf     = (float*)(concat + 3670016); // f32 residual [4096][256]

  dim3 blk(256);

  trans_attn_t<<<dim3(288), blk, 0, stream>>>(Wk, Wv, Wq, Wo, Wkvqt, Wot);

  // merged projections: K|V input (512 blocks) + K|V|Q state (640 blocks)
  proj2<<<dim3(1152), blk, 0, stream>>>(input, state, Wkvqt, bk, bv, bq,
                                        ik, ivT, mk, mv, qbuf);

  attn_kernel<<<dim3(8, 4, 8), blk, 0, stream>>>(qbuf, ik, ivT, mk, mv, concat);

  // Wo: split-K (4 x 512) -> f32 partials, 256 blocks
  gemm_bt<<<dim3(32, 2, 4), blk, 0, stream>>>(concat, nullptr, Wot, bo, nullptr, nullptr,
                                              nullptr, nullptr, nullptr, wo_parts,
                                              4096, 256, 2048, 512, 0, 7, 0);
  // LN1 + FFN weight transpose merged (independent; saves one launch gap)
  ln4_trffn<<<dim3(1664), blk, 0, stream>>>(wo_parts, state, ln1g, ln1b, x, xf,
                                            W_in, Wg_nl, Wg_l, Wg_o, Wffn);

  gemm_bt<<<dim3(32, 8), blk, 0, stream>>>(x, nullptr, Wffn, b_in, nullptr, nullptr,
                                           hbuf, nullptr, nullptr, nullptr,
                                           4096, 1024, 256, 256, 0, 0, 1);
  // fused Wg_nl|Wg_l: N=2048, relu on first half
  gemm_bt<<<dim3(32, 16), blk, 0, stream>>>(hbuf, nullptr, Wffn + 262144, bg_nl, bg_l, nullptr,
                                            t12, nullptr, nullptr, nullptr,
                                            4096, 2048, 1024, 1024, 0, 6, 0);
  // Wg_o with gating fused into the stager: split-K (4 x 256) -> f32 partials
  gemm_bt<<<dim3(32, 2, 4), blk, 0, stream>>>(t12, nullptr, Wffn + 2359296, bg_o, nullptr, nullptr,
                                              nullptr, nullptr, nullptr, ff_parts,
                                              4096, 256, 1024, 256, 2, 7, 0);
  ln4_kernel<<<dim3(1024), blk, 0, stream>>>(ff_parts, xf, ln2g, ln2b, nullptr, out);
}